// Round 6
// baseline (170.660 us; speedup 1.0000x reference)
//
#include <hip/hip_runtime.h>

// AttentionBlock: GroupNorm -> conv1x1 QKV -> MHA (NH=8, DH=64, HW=1024) -> conv1x1 proj -> residual
// Inputs/outputs fp32; internal compute bf16 MFMA (16x16x32 GEMMs, 32x32x16 attn), fp32 accum.
//
// This revision (attn only; prep/qkv/proj = round-2 verified forms):
//  - attn K/V LDS staging REMOVED (m169: L2-fit data, staging was overhead). K/V fragments are
//    read directly from XCD-local L2/L1 (bh pinned to one XCD by the block swizzle; all 4 waves
//    of a block read identical fragments -> L1 hits). Main loop: ZERO barriers.
//  - P round-trip through wave-private swizzled LDS (harness-verified in rounds 2/4).
//    The round-5 permlane in-register P path produced NaN and is shelved (unverified lane map).
//
// Layouts (async global_load_lds staging only in the GEMMs, 16B/lane, lane-contiguous 1KB pieces):
//   H    (groupnorm out): chunked(n,c) = (((n>>6)*16 + (c>>5))*4 + ((c>>3)&3))*512 + (n&63)*8 + (c&7)
//   qbuf/kbuf: per-head chunked [bh][16 s-tiles][8 d-chunks][64 s][8 d]
//   vt  : per-head transposed  [bh][16 j-tiles][8 j-chunks][64 d][8 j]
//   P_in (attn out): [c>>3][n(8192)][8 c]   (reuses H region)
//   wq/wp: chunked weights

typedef float  f32x4  __attribute__((ext_vector_type(4)));
typedef float  f32x16 __attribute__((ext_vector_type(16)));
typedef __bf16 bf16x8 __attribute__((ext_vector_type(8)));
typedef __bf16 bf16x4 __attribute__((ext_vector_type(4)));
typedef __bf16 bf16x2 __attribute__((ext_vector_type(2)));

#define MFMA(a, b, c)   __builtin_amdgcn_mfma_f32_16x16x32_bf16(a, b, c, 0, 0, 0)
#define MFMA32(a, b, c) __builtin_amdgcn_mfma_f32_32x32x16_bf16(a, b, c, 0, 0, 0)

__device__ __forceinline__ void async16(const __bf16* g, __bf16* l) {
  __builtin_amdgcn_global_load_lds((const __attribute__((address_space(1))) void*)g,
                                   (__attribute__((address_space(3))) void*)l, 16, 0, 0);
}

__device__ __forceinline__ int chk(int n, int c) {
  return ((((n >> 6) * 16 + (c >> 5)) * 4 + ((c >> 3) & 3)) * 512) + (n & 63) * 8 + (c & 7);
}

// ---------------------------------------------------------------- GroupNorm + weight-convert (grid-fused)
// blocks [0,256): groupnorm (b,g). blocks [256,768): fp32->bf16 chunked weight convert.
__global__ __launch_bounds__(512) void prep_k(const float* __restrict__ x,
                                              const float* __restrict__ gamma,
                                              const float* __restrict__ beta,
                                              __bf16* __restrict__ Hout,
                                              const float* __restrict__ qw, __bf16* __restrict__ dq,
                                              const float* __restrict__ pw, __bf16* __restrict__ dp) {
  __shared__ __bf16 xs[16 * 1032];
  __shared__ float  red[16];
  __shared__ float  ga[16], be[16], stat[2];
  const int tid = threadIdx.x;

  if (blockIdx.x >= 256) {        // ---- weight convert path (no LDS, no barriers)
    int i = ((blockIdx.x - 256) * 512 + tid) * 4;
    const float* src = (i < 786432) ? qw : pw;
    __bf16* dst = (i < 786432) ? dq : dp;
    int j = (i < 786432) ? i : (i - 786432);
    int m = j >> 9, k = j & 511;
    float4 v = *(const float4*)(src + j);
    bf16x4 o;
    o[0] = (__bf16)v.x; o[1] = (__bf16)v.y; o[2] = (__bf16)v.z; o[3] = (__bf16)v.w;
    *(bf16x4*)(dst + chk(m, k)) = o;
    return;
  }

  const int w = tid >> 6, l = tid & 63;
  const int bg = blockIdx.x, b = bg >> 5, g = bg & 31, c0 = g * 16;
  const float* xg = x + b * 524288 + c0 * 1024;

  float sum = 0.f, sq = 0.f;
#pragma unroll
  for (int p = 0; p < 8; p++) {
    int idx = p * 2048 + tid * 4;
    float4 v = *(const float4*)(xg + idx);
    int c = idx >> 10, s = idx & 1023;
    bf16x4 o;
    o[0] = (__bf16)v.x; o[1] = (__bf16)v.y; o[2] = (__bf16)v.z; o[3] = (__bf16)v.w;
    *(bf16x4*)(&xs[c * 1032 + s]) = o;
    sum += v.x + v.y + v.z + v.w;
    sq  += v.x * v.x + v.y * v.y + v.z * v.z + v.w * v.w;
  }
#pragma unroll
  for (int o = 32; o > 0; o >>= 1) { sum += __shfl_down(sum, o); sq += __shfl_down(sq, o); }
  if (l == 0) { red[w * 2] = sum; red[w * 2 + 1] = sq; }
  __syncthreads();
  if (tid == 0) {
    float S = 0.f, Q = 0.f;
#pragma unroll
    for (int i = 0; i < 8; i++) { S += red[i * 2]; Q += red[i * 2 + 1]; }
    float mean = S * (1.f / 16384.f);
    float var  = Q * (1.f / 16384.f) - mean * mean;
    stat[0] = mean; stat[1] = rsqrtf(var + 1e-5f);
  }
  if (tid < 16) { ga[tid] = gamma[c0 + tid]; be[tid] = beta[c0 + tid]; }
  __syncthreads();
  const float mean = stat[0], rstd = stat[1];
#pragma unroll
  for (int p = 0; p < 2; p++) {
    int s = p * 512 + tid;
    int n = b * 1024 + s;
    bf16x8 o0, o1;
#pragma unroll
    for (int c = 0; c < 8; c++) {
      float f = (float)xs[c * 1032 + s];
      o0[c] = (__bf16)((f - mean) * rstd * ga[c] + be[c]);
    }
#pragma unroll
    for (int c = 8; c < 16; c++) {
      float f = (float)xs[c * 1032 + s];
      o1[c - 8] = (__bf16)((f - mean) * rstd * ga[c] + be[c]);
    }
    *(bf16x8*)(Hout + chk(n, c0)) = o0;
    *(bf16x8*)(Hout + chk(n, c0 + 8)) = o1;
  }
}

// ---------------------------------------------------------------- QKV GEMM (dbuf async, 1 barrier/iter)
__global__ __launch_bounds__(256) void gemm_qkv_k(const __bf16* __restrict__ W,
                                                  const float* __restrict__ bias,
                                                  const __bf16* __restrict__ H,
                                                  __bf16* __restrict__ qbuf,
                                                  __bf16* __restrict__ kbuf,
                                                  __bf16* __restrict__ vt) {
  __shared__ union {
    struct { __bf16 a[2][4096]; __bf16 b[2][4096]; } ab;   // chunk-major [4 ch][128 r][8]
    __bf16 cs[128 * 136];                                  // epilogue transpose [n][o] pad 8
  } lds;
  const int tid = threadIdx.x;
  const int w = tid >> 6, l = tid & 63, quad = l >> 4, li = l & 15;
  const int wr = w >> 1, wc = w & 1;
  const int mblk = blockIdx.x >> 6, nblk = blockIdx.x & 63;
  const int m0 = mblk * 128, n0 = nblk * 128;

  f32x4 acc[4][4];
#pragma unroll
  for (int i = 0; i < 4; i++)
#pragma unroll
    for (int j = 0; j < 4; j++) acc[i][j] = f32x4{0.f, 0.f, 0.f, 0.f};

  const __bf16* Ag = W + (((m0 >> 6) * 16) * 4 + w) * 512 + l * 8;
  const __bf16* Bg = H + (((n0 >> 6) * 16) * 4 + w) * 512 + l * 8;
  const int halfA = 16 * 4 * 512;

  async16(Ag,         &lds.ab.a[0][w * 1024]);
  async16(Ag + halfA, &lds.ab.a[0][w * 1024 + 512]);
  async16(Bg,         &lds.ab.b[0][w * 1024]);
  async16(Bg + halfA, &lds.ab.b[0][w * 1024 + 512]);

#pragma unroll 1
  for (int kt = 0; kt < 16; kt++) {
    int cur = kt & 1, nxt = cur ^ 1;
    __syncthreads();
    if (kt < 15) {
      int ko = (kt + 1) * 2048;
      async16(Ag + ko,          &lds.ab.a[nxt][w * 1024]);
      async16(Ag + halfA + ko,  &lds.ab.a[nxt][w * 1024 + 512]);
      async16(Bg + ko,          &lds.ab.b[nxt][w * 1024]);
      async16(Bg + halfA + ko,  &lds.ab.b[nxt][w * 1024 + 512]);
    }
    bf16x8 af[4], bfr[4];
#pragma unroll
    for (int i = 0; i < 4; i++)
      af[i] = *(const bf16x8*)(&lds.ab.a[cur][quad * 1024 + (wr * 64 + i * 16 + li) * 8]);
#pragma unroll
    for (int i = 0; i < 4; i++)
      bfr[i] = *(const bf16x8*)(&lds.ab.b[cur][quad * 1024 + (wc * 64 + i * 16 + li) * 8]);
#pragma unroll
    for (int i = 0; i < 4; i++)
#pragma unroll
      for (int j = 0; j < 4; j++) acc[i][j] = MFMA(af[i], bfr[j], acc[i][j]);
  }

  const int t = m0 >> 9;          // 0=q 1=k 2=v (block-uniform)
  const int cbase = m0 & 511;
  __syncthreads();                // mainloop LDS reads done before union reuse
#pragma unroll
  for (int mi = 0; mi < 4; mi++) {
    int olocal = wr * 64 + mi * 16 + quad * 4;
    float bs[4];
#pragma unroll
    for (int r = 0; r < 4; r++) bs[r] = bias[m0 + olocal + r];
#pragma unroll
    for (int ni = 0; ni < 4; ni++) {
      int nlocal = wc * 64 + ni * 16 + li;
      bf16x4 pk;
#pragma unroll
      for (int r = 0; r < 4; r++) {
        float f = acc[mi][ni][r] + bs[r];
        if (t == 0) f *= 0.180336880f;     // 0.125 * log2(e): exp2-domain softmax
        pk[r] = (__bf16)f;
      }
      *(bf16x4*)(&lds.cs[nlocal * 136 + olocal]) = pk;
    }
  }
  __syncthreads();
  const int bb = n0 >> 10, s0 = n0 & 1023;
  if (t < 2) {
    __bf16* dst = (t == 0) ? qbuf : kbuf;
    const int nh0 = cbase >> 6;
#pragma unroll
    for (int p = 0; p < 8; p++) {
      int idx = p * 256 + tid;
      int oc = idx & 15, nloc = idx >> 4;
      uint4 val = *(const uint4*)(&lds.cs[nloc * 136 + oc * 8]);
      int bh = bb * 8 + nh0 + (oc >> 3);
      int s = s0 + nloc, d0 = (oc & 7) * 8;
      *(uint4*)(dst + (((bh * 16 + (s >> 6)) * 8 + (d0 >> 3)) * 64 + (s & 63)) * 8) = val;
    }
  } else {
    // v -> per-head transposed chunked: vt[bh][j>>6][(j>>3)&7][d][j&7]
#pragma unroll
    for (int p = 0; p < 8; p++) {
      int idx = p * 256 + tid;
      int o = idx & 127, ng = idx >> 7;
      int c = cbase + o, nh2 = c >> 6, d = c & 63;
      int bh = bb * 8 + nh2;
      int j0 = s0 + ng * 8;
      bf16x8 vv;
#pragma unroll
      for (int jj = 0; jj < 8; jj++) vv[jj] = lds.cs[(ng * 8 + jj) * 136 + o];
      *(bf16x8*)(vt + (((bh * 16 + (j0 >> 6)) * 8 + ((j0 >> 3) & 7)) * 64 + d) * 8) = vv;
    }
  }
}

// ---------------------------------------------------------------- Attention (flash, no-max softmax, 32x32 MFMA)
// grid 512 = (bh, qt of 128 q-rows), XCD-swizzled (bh low bits -> same-bh blocks share an XCD L2).
// NO K/V LDS staging (m169: L2/L1-resident); NO barriers in the KV loop.
// P round-trips wave-private swizzled LDS (verified rounds 2/4).
// 32x32x16 fragment maps: A/B: row|col = lane&31, k = (lane>>5)*8 + e
//                         C/D: col = lane&31, row = (reg&3) + 8*(reg>>2) + 4*(lane>>5)
__global__ __launch_bounds__(256) void attn_k(const __bf16* __restrict__ qb,
                                              const __bf16* __restrict__ kb,
                                              const __bf16* __restrict__ vt,
                                              __bf16* __restrict__ pin) {
  __shared__ __bf16 PO[8192];        // P: per-wave [32 i][64 j] XOR-swizzled (4KB/wave); epilogue O
  const int tid = threadIdx.x;
  const int w = tid >> 6, l = tid & 63, hi = l >> 5, i32 = l & 31;
  const int x = blockIdx.x;
  const int qt = (x >> 3) & 7;
  const int bh = (x & 7) | ((x >> 6) << 3);    // low 3 bits follow XCD round-robin
  const int b = bh >> 3, nh = bh & 7;
  const __bf16* Qg = qb + bh * 65536;
  const __bf16* Kg = kb + bh * 65536;
  const __bf16* Vg = vt + bh * 65536;

  // Q -> registers: B-frag for col i = i32, d = ks*16 + hi*8 + e (qbuf chunk dch = ks*2+hi)
  const int s = qt * 128 + w * 32 + i32;
  bf16x8 qf[4];
#pragma unroll
  for (int ks = 0; ks < 4; ks++)
    qf[ks] = *(const bf16x8*)(Qg + ((s >> 6) * 8 + ks * 2 + hi) * 512 + (s & 63) * 8);

  const int swz = (i32 & 7) << 4;    // P bank-swizzle (store 8B / read 16B granules)
  char* Pw = (char*)PO + w * 4096;
  float lsum = 0.f;
  f32x16 oacc[2];
#pragma unroll
  for (int r = 0; r < 16; r++) { oacc[0][r] = 0.f; oacc[1][r] = 0.f; }

#pragma unroll 1
  for (int kv = 0; kv < 16; kv++) {
    const __bf16* Kt = Kg + kv * 4096;
    const __bf16* Vt = Vg + kv * 4096;
#pragma unroll
    for (int jt = 0; jt < 2; jt++) {
      // S^T [32 j][32 i] for this jt: A = K rows j, B = Q cols i, k-dim d = 4 ks of 16
      f32x16 st;
#pragma unroll
      for (int r = 0; r < 16; r++) st[r] = 0.f;
#pragma unroll
      for (int ks = 0; ks < 4; ks++) {
        bf16x8 kf = *(const bf16x8*)(Kt + (ks * 2 + hi) * 512 + (jt * 32 + i32) * 8);
        st = MFMA32(kf, qf[ks], st);
      }
      // P = exp2(S); lane holds P[i=i32][j = jt*32 + q2*8 + 4*hi + m]; store swizzled
#pragma unroll
      for (int q2 = 0; q2 < 4; q2++) {
        float p0 = __builtin_amdgcn_exp2f(st[q2 * 4 + 0]);
        float p1 = __builtin_amdgcn_exp2f(st[q2 * 4 + 1]);
        float p2 = __builtin_amdgcn_exp2f(st[q2 * 4 + 2]);
        float p3 = __builtin_amdgcn_exp2f(st[q2 * 4 + 3]);
        lsum += (p0 + p1) + (p2 + p3);
        bf16x4 pk;
        pk[0] = (__bf16)p0; pk[1] = (__bf16)p1; pk[2] = (__bf16)p2; pk[3] = (__bf16)p3;
        *(bf16x4*)(Pw + ((i32 * 128 + jt * 64 + q2 * 16 + hi * 8) ^ swz)) = pk;
      }
      // O += P.V for this jt's two k-halves (P wave-private; same-wave ds ordering)
#pragma unroll
      for (int h = 0; h < 2; h++) {
        int js = jt * 2 + h;
        bf16x8 pf = *(const bf16x8*)(Pw + ((i32 * 128 + js * 32 + hi * 16) ^ swz));
#pragma unroll
        for (int dt = 0; dt < 2; dt++) {
          bf16x8 vf = *(const bf16x8*)(Vt + (js * 2 + hi) * 512 + (dt * 32 + i32) * 8);
          oacc[dt] = MFMA32(pf, vf, oacc[dt]);
        }
      }
    }
  }

  // deferred l reduction: lane l and l^32 hold complementary j-halves of row i=i32
  lsum += __shfl_xor(lsum, 32);
  const float inv = 1.f / lsum;
  __syncthreads();                   // all waves' P reads done before PO epilogue reuse

  // O -> LDS [n' = (i&15)*64 + d][8 c] with c&7 = w*2 + (i>>4); regs r and r+8 differ by i += 16
#pragma unroll
  for (int dt = 0; dt < 2; dt++) {
#pragma unroll
    for (int r = 0; r < 8; r++) {
      int ilo = (r & 3) + 8 * (r >> 2) + 4 * hi;     // 0..15
      float iblo = __shfl(inv, ilo);
      float ibhi = __shfl(inv, ilo + 16);
      bf16x2 ov;
      ov[0] = (__bf16)(oacc[dt][r]     * iblo);
      ov[1] = (__bf16)(oacc[dt][r + 8] * ibhi);
      *(bf16x2*)((char*)PO + (ilo * 64 + dt * 32 + i32) * 16 + w * 4) = ov;
    }
  }
  __syncthreads();
  // block output = contiguous 8192 bf16 at pin[(nh*8+qt)][b*1024 .. +1024][8]
  __bf16* Pg = pin + (nh * 8 + qt) * 65536 + b * 8192;
#pragma unroll
  for (int p = 0; p < 4; p++) {
    int idx = p * 256 + tid;
    *(bf16x8*)(Pg + idx * 8) = *(const bf16x8*)((const char*)PO + idx * 16);
  }
}

// ---------------------------------------------------------------- Proj GEMM + residual (64x128 tiles)
__global__ __launch_bounds__(256) void gemm_proj_k(const __bf16* __restrict__ W,
                                                   const float* __restrict__ bias,
                                                   const __bf16* __restrict__ P,
                                                   const float* __restrict__ x,
                                                   float* __restrict__ out) {
  __shared__ __bf16 AL[2][2048];    // [4 ch][64 r][8]
  __shared__ __bf16 BL[2][4096];    // [4 cg][128 r][8]
  const int tid = threadIdx.x;
  const int w = tid >> 6, l = tid & 63, quad = l >> 4, li = l & 15;
  const int wr = w >> 1, wc = w & 1;
  const int mblk = blockIdx.x >> 6, nblk = blockIdx.x & 63;
  const int m0 = mblk * 64, n0 = nblk * 128;

  f32x4 acc[2][4];
#pragma unroll
  for (int i = 0; i < 2; i++)
#pragma unroll
    for (int j = 0; j < 4; j++) acc[i][j] = f32x4{0.f, 0.f, 0.f, 0.f};

  const __bf16* Ag = W + ((mblk * 16) * 4 + w) * 512 + l * 8;
  const __bf16* Bg = P + w * 65536 + (n0 + l) * 8;   // [cg][n][8]; kt stride = 4*65536

  async16(Ag,       &AL[0][w * 512]);
  async16(Bg,       &BL[0][w * 1024]);
  async16(Bg + 512, &BL[0][w * 1024 + 512]);

#pragma unroll 1
  for (int kt = 0; kt < 16; kt++) {
    int cur = kt & 1, nxt = cur ^ 1;
    __syncthreads();
    if (kt < 15) {
      int koA = (kt + 1) * 2048;
      int koB = (kt + 1) * 262144;
      async16(Ag + koA,       &AL[nxt][w * 512]);
      async16(Bg + koB,       &BL[nxt][w * 1024]);
      async16(Bg + koB + 512, &BL[nxt][w * 1024 + 512]);
    }
    bf16x8 af[2], bfr[4];
#pragma unroll
    for (int i = 0; i < 2; i++)
      af[i] = *(const bf16x8*)(&AL[cur][quad * 512 + (wr * 32 + i * 16 + li) * 8]);
#pragma unroll
    for (int j = 0; j < 4; j++)
      bfr[j] = *(const bf16x8*)(&BL[cur][quad * 1024 + (wc * 64 + j * 16 + li) * 8]);
#pragma unroll
    for (int i = 0; i < 2; i++)
#pragma unroll
      for (int j = 0; j < 4; j++) acc[i][j] = MFMA(af[i], bfr[j], acc[i][j]);
  }

  const int bb = n0 >> 10;
#pragma unroll
  for (int mi = 0; mi < 2; mi++) {
    int o = m0 + wr * 32 + mi * 16 + quad * 4;
    float bs[4];
#pragma unroll
    for (int r = 0; r < 4; r++) bs[r] = bias[o + r];
#pragma unroll
    for (int ni = 0; ni < 4; ni++) {
      int n = n0 + wc * 64 + ni * 16 + li;
      int s = n & 1023;
#pragma unroll
      for (int r = 0; r < 4; r++) {
        int a = (bb * 512 + o + r) * 1024 + s;
        out[a] = acc[mi][ni][r] + bs[r] + x[a];
      }
    }
  }
}

// ---------------------------------------------------------------- launch
extern "C" void kernel_launch(void* const* d_in, const int* in_sizes, int n_in,
                              void* d_out, int out_size, void* d_ws, size_t ws_size,
                              hipStream_t stream) {
  const float* x      = (const float*)d_in[0];
  const float* gamma  = (const float*)d_in[1];
  const float* beta   = (const float*)d_in[2];
  const float* qkv_w  = (const float*)d_in[3];
  const float* qkv_b  = (const float*)d_in[4];
  const float* proj_w = (const float*)d_in[5];
  const float* proj_b = (const float*)d_in[6];

  __bf16* ws   = (__bf16*)d_ws;
  __bf16* H    = ws;                 // chunked groupnorm out; reused as P_in [cg][n][8]
  __bf16* qbuf = ws + 4194304;
  __bf16* kbuf = ws + 8388608;
  __bf16* vt   = ws + 12582912;
  __bf16* wq   = ws + 16777216;
  __bf16* wp   = ws + 17563648;

  prep_k<<<768, 512, 0, stream>>>(x, gamma, beta, H, qkv_w, wq, proj_w, wp);
  gemm_qkv_k<<<768, 256, 0, stream>>>(wq, qkv_b, H, qbuf, kbuf, vt);
  attn_k<<<512, 256, 0, stream>>>(qbuf, kbuf, vt, H);
  gemm_proj_k<<<512, 256, 0, stream>>>(wp, proj_b, H, x, (float*)d_out);
}

// Round 7
// 135.903 us; speedup vs baseline: 1.2557x; 1.2557x over previous
//
#include <hip/hip_runtime.h>

// AttentionBlock: GroupNorm -> conv1x1 QKV -> MHA (NH=8, DH=64, HW=1024) -> conv1x1 proj -> residual
// Inputs/outputs fp32; internal compute bf16 MFMA (16x16x32 GEMMs, 32x32x16 attn), fp32 accum.
//
// Round-6 lesson: K/V LDS staging is REQUIRED (unstaged = 4x L1/L2 traffic at 2 blk/CU -> 62us,
// +27us regression). This revision = round-2 staged attention + T12 in-register P:
//   P never touches LDS. v_cvt_pk pairs + v_permlane32_swap_b32 (vdst=q2-even pack, vsrc=q2-odd
//   pack; vdst[l>=32]<-vsrc[l-32], vsrc[l<32]<-vdst[l+32]) assemble the PV A-fragment directly
//   from the S^T C-fragment. Round-5 NaN was the inverted vdst/vsrc order.
// attn LDS: 32KB (K/V dbuf); epilogue O staging reuses the K region.
//
// Layouts (async global_load_lds staging, 16B/lane, lane-contiguous 1KB pieces):
//   H    (groupnorm out): chunked(n,c) = (((n>>6)*16 + (c>>5))*4 + ((c>>3)&3))*512 + (n&63)*8 + (c&7)
//   qbuf/kbuf: per-head chunked [bh][16 s-tiles][8 d-chunks][64 s][8 d]
//   vt  : per-head transposed  [bh][16 j-tiles][8 j-chunks][64 d][8 j]
//   P_in (attn out): [c>>3][n(8192)][8 c]   (reuses H region)
//   wq/wp: chunked weights

typedef float  f32x4  __attribute__((ext_vector_type(4)));
typedef float  f32x16 __attribute__((ext_vector_type(16)));
typedef __bf16 bf16x8 __attribute__((ext_vector_type(8)));
typedef __bf16 bf16x4 __attribute__((ext_vector_type(4)));
typedef __bf16 bf16x2 __attribute__((ext_vector_type(2)));
typedef unsigned u32x4 __attribute__((ext_vector_type(4)));

#define MFMA(a, b, c)   __builtin_amdgcn_mfma_f32_16x16x32_bf16(a, b, c, 0, 0, 0)
#define MFMA32(a, b, c) __builtin_amdgcn_mfma_f32_32x32x16_bf16(a, b, c, 0, 0, 0)

__device__ __forceinline__ void async16(const __bf16* g, __bf16* l) {
  __builtin_amdgcn_global_load_lds((const __attribute__((address_space(1))) void*)g,
                                   (__attribute__((address_space(3))) void*)l, 16, 0, 0);
}

__device__ __forceinline__ int chk(int n, int c) {
  return ((((n >> 6) * 16 + (c >> 5)) * 4 + ((c >> 3) & 3)) * 512) + (n & 63) * 8 + (c & 7);
}

// bf16 pair pack (compiler emits v_cvt_pk_bf16_f32)
__device__ __forceinline__ unsigned pk2(float x, float y) {
  bf16x2 t; t[0] = (__bf16)x; t[1] = (__bf16)y;
  return __builtin_bit_cast(unsigned, t);
}

// ---------------------------------------------------------------- GroupNorm + weight-convert (grid-fused)
// blocks [0,256): groupnorm (b,g). blocks [256,768): fp32->bf16 chunked weight convert.
__global__ __launch_bounds__(512) void prep_k(const float* __restrict__ x,
                                              const float* __restrict__ gamma,
                                              const float* __restrict__ beta,
                                              __bf16* __restrict__ Hout,
                                              const float* __restrict__ qw, __bf16* __restrict__ dq,
                                              const float* __restrict__ pw, __bf16* __restrict__ dp) {
  __shared__ __bf16 xs[16 * 1032];
  __shared__ float  red[16];
  __shared__ float  ga[16], be[16], stat[2];
  const int tid = threadIdx.x;

  if (blockIdx.x >= 256) {        // ---- weight convert path (no LDS, no barriers)
    int i = ((blockIdx.x - 256) * 512 + tid) * 4;
    const float* src = (i < 786432) ? qw : pw;
    __bf16* dst = (i < 786432) ? dq : dp;
    int j = (i < 786432) ? i : (i - 786432);
    int m = j >> 9, k = j & 511;
    float4 v = *(const float4*)(src + j);
    bf16x4 o;
    o[0] = (__bf16)v.x; o[1] = (__bf16)v.y; o[2] = (__bf16)v.z; o[3] = (__bf16)v.w;
    *(bf16x4*)(dst + chk(m, k)) = o;
    return;
  }

  const int w = tid >> 6, l = tid & 63;
  const int bg = blockIdx.x, b = bg >> 5, g = bg & 31, c0 = g * 16;
  const float* xg = x + b * 524288 + c0 * 1024;

  float sum = 0.f, sq = 0.f;
#pragma unroll
  for (int p = 0; p < 8; p++) {
    int idx = p * 2048 + tid * 4;
    float4 v = *(const float4*)(xg + idx);
    int c = idx >> 10, s = idx & 1023;
    bf16x4 o;
    o[0] = (__bf16)v.x; o[1] = (__bf16)v.y; o[2] = (__bf16)v.z; o[3] = (__bf16)v.w;
    *(bf16x4*)(&xs[c * 1032 + s]) = o;
    sum += v.x + v.y + v.z + v.w;
    sq  += v.x * v.x + v.y * v.y + v.z * v.z + v.w * v.w;
  }
#pragma unroll
  for (int o = 32; o > 0; o >>= 1) { sum += __shfl_down(sum, o); sq += __shfl_down(sq, o); }
  if (l == 0) { red[w * 2] = sum; red[w * 2 + 1] = sq; }
  __syncthreads();
  if (tid == 0) {
    float S = 0.f, Q = 0.f;
#pragma unroll
    for (int i = 0; i < 8; i++) { S += red[i * 2]; Q += red[i * 2 + 1]; }
    float mean = S * (1.f / 16384.f);
    float var  = Q * (1.f / 16384.f) - mean * mean;
    stat[0] = mean; stat[1] = rsqrtf(var + 1e-5f);
  }
  if (tid < 16) { ga[tid] = gamma[c0 + tid]; be[tid] = beta[c0 + tid]; }
  __syncthreads();
  const float mean = stat[0], rstd = stat[1];
#pragma unroll
  for (int p = 0; p < 2; p++) {
    int s = p * 512 + tid;
    int n = b * 1024 + s;
    bf16x8 o0, o1;
#pragma unroll
    for (int c = 0; c < 8; c++) {
      float f = (float)xs[c * 1032 + s];
      o0[c] = (__bf16)((f - mean) * rstd * ga[c] + be[c]);
    }
#pragma unroll
    for (int c = 8; c < 16; c++) {
      float f = (float)xs[c * 1032 + s];
      o1[c - 8] = (__bf16)((f - mean) * rstd * ga[c] + be[c]);
    }
    *(bf16x8*)(Hout + chk(n, c0)) = o0;
    *(bf16x8*)(Hout + chk(n, c0 + 8)) = o1;
  }
}

// ---------------------------------------------------------------- QKV GEMM (dbuf async, 1 barrier/iter)
__global__ __launch_bounds__(256) void gemm_qkv_k(const __bf16* __restrict__ W,
                                                  const float* __restrict__ bias,
                                                  const __bf16* __restrict__ H,
                                                  __bf16* __restrict__ qbuf,
                                                  __bf16* __restrict__ kbuf,
                                                  __bf16* __restrict__ vt) {
  __shared__ union {
    struct { __bf16 a[2][4096]; __bf16 b[2][4096]; } ab;   // chunk-major [4 ch][128 r][8]
    __bf16 cs[128 * 136];                                  // epilogue transpose [n][o] pad 8
  } lds;
  const int tid = threadIdx.x;
  const int w = tid >> 6, l = tid & 63, quad = l >> 4, li = l & 15;
  const int wr = w >> 1, wc = w & 1;
  const int mblk = blockIdx.x >> 6, nblk = blockIdx.x & 63;
  const int m0 = mblk * 128, n0 = nblk * 128;

  f32x4 acc[4][4];
#pragma unroll
  for (int i = 0; i < 4; i++)
#pragma unroll
    for (int j = 0; j < 4; j++) acc[i][j] = f32x4{0.f, 0.f, 0.f, 0.f};

  const __bf16* Ag = W + (((m0 >> 6) * 16) * 4 + w) * 512 + l * 8;
  const __bf16* Bg = H + (((n0 >> 6) * 16) * 4 + w) * 512 + l * 8;
  const int halfA = 16 * 4 * 512;

  async16(Ag,         &lds.ab.a[0][w * 1024]);
  async16(Ag + halfA, &lds.ab.a[0][w * 1024 + 512]);
  async16(Bg,         &lds.ab.b[0][w * 1024]);
  async16(Bg + halfA, &lds.ab.b[0][w * 1024 + 512]);

#pragma unroll 1
  for (int kt = 0; kt < 16; kt++) {
    int cur = kt & 1, nxt = cur ^ 1;
    __syncthreads();
    if (kt < 15) {
      int ko = (kt + 1) * 2048;
      async16(Ag + ko,          &lds.ab.a[nxt][w * 1024]);
      async16(Ag + halfA + ko,  &lds.ab.a[nxt][w * 1024 + 512]);
      async16(Bg + ko,          &lds.ab.b[nxt][w * 1024]);
      async16(Bg + halfA + ko,  &lds.ab.b[nxt][w * 1024 + 512]);
    }
    bf16x8 af[4], bfr[4];
#pragma unroll
    for (int i = 0; i < 4; i++)
      af[i] = *(const bf16x8*)(&lds.ab.a[cur][quad * 1024 + (wr * 64 + i * 16 + li) * 8]);
#pragma unroll
    for (int i = 0; i < 4; i++)
      bfr[i] = *(const bf16x8*)(&lds.ab.b[cur][quad * 1024 + (wc * 64 + i * 16 + li) * 8]);
#pragma unroll
    for (int i = 0; i < 4; i++)
#pragma unroll
      for (int j = 0; j < 4; j++) acc[i][j] = MFMA(af[i], bfr[j], acc[i][j]);
  }

  const int t = m0 >> 9;          // 0=q 1=k 2=v (block-uniform)
  const int cbase = m0 & 511;
  __syncthreads();                // mainloop LDS reads done before union reuse
#pragma unroll
  for (int mi = 0; mi < 4; mi++) {
    int olocal = wr * 64 + mi * 16 + quad * 4;
    float bs[4];
#pragma unroll
    for (int r = 0; r < 4; r++) bs[r] = bias[m0 + olocal + r];
#pragma unroll
    for (int ni = 0; ni < 4; ni++) {
      int nlocal = wc * 64 + ni * 16 + li;
      bf16x4 pk;
#pragma unroll
      for (int r = 0; r < 4; r++) {
        float f = acc[mi][ni][r] + bs[r];
        if (t == 0) f *= 0.180336880f;     // 0.125 * log2(e): exp2-domain softmax
        pk[r] = (__bf16)f;
      }
      *(bf16x4*)(&lds.cs[nlocal * 136 + olocal]) = pk;
    }
  }
  __syncthreads();
  const int bb = n0 >> 10, s0 = n0 & 1023;
  if (t < 2) {
    __bf16* dst = (t == 0) ? qbuf : kbuf;
    const int nh0 = cbase >> 6;
#pragma unroll
    for (int p = 0; p < 8; p++) {
      int idx = p * 256 + tid;
      int oc = idx & 15, nloc = idx >> 4;
      uint4 val = *(const uint4*)(&lds.cs[nloc * 136 + oc * 8]);
      int bh = bb * 8 + nh0 + (oc >> 3);
      int s = s0 + nloc, d0 = (oc & 7) * 8;
      *(uint4*)(dst + (((bh * 16 + (s >> 6)) * 8 + (d0 >> 3)) * 64 + (s & 63)) * 8) = val;
    }
  } else {
    // v -> per-head transposed chunked: vt[bh][j>>6][(j>>3)&7][d][j&7]
#pragma unroll
    for (int p = 0; p < 8; p++) {
      int idx = p * 256 + tid;
      int o = idx & 127, ng = idx >> 7;
      int c = cbase + o, nh2 = c >> 6, d = c & 63;
      int bh = bb * 8 + nh2;
      int j0 = s0 + ng * 8;
      bf16x8 vv;
#pragma unroll
      for (int jj = 0; jj < 8; jj++) vv[jj] = lds.cs[(ng * 8 + jj) * 136 + o];
      *(bf16x8*)(vt + (((bh * 16 + (j0 >> 6)) * 8 + ((j0 >> 3) & 7)) * 64 + d) * 8) = vv;
    }
  }
}

// ---------------------------------------------------------------- Attention (flash, no-max softmax, 32x32 MFMA)
// grid 512 = (bh, qt of 128 q-rows), XCD-swizzled. Wave w: q-rows [w*32, w*32+32).
// K/V staged via dbuf async (round-6: staging is required). P fully in registers (T12).
// LDS 32 KB; epilogue reuses the K region.
// 32x32x16 fragment maps: A/B: row|col = lane&31, k = (lane>>5)*8 + e
//                         C/D: col = lane&31, row = (reg&3) + 8*(reg>>2) + 4*(lane>>5)
__global__ __launch_bounds__(256) void attn_k(const __bf16* __restrict__ qb,
                                              const __bf16* __restrict__ kb,
                                              const __bf16* __restrict__ vt,
                                              __bf16* __restrict__ pin) {
  __shared__ __bf16 KC[2][4096];     // [8 dch][64 j][8 d]; epilogue O reuses these 16 KB
  __shared__ __bf16 VC[2][4096];     // [8 jch][64 d][8 j]
  const int tid = threadIdx.x;
  const int w = tid >> 6, l = tid & 63, hi = l >> 5, i32 = l & 31;
  const int x = blockIdx.x;
  const int qt = (x >> 3) & 7;
  const int bh = (x & 7) | ((x >> 6) << 3);    // low 3 bits follow XCD round-robin
  const int b = bh >> 3, nh = bh & 7;
  const __bf16* Qg = qb + bh * 65536;
  const __bf16* Kg = kb + bh * 65536;
  const __bf16* Vg = vt + bh * 65536;

  // stage K0 + V0 (4 async16/wave), then Q -> registers
#pragma unroll
  for (int p = 0; p < 2; p++) {
    int ch = w + 4 * p;
    async16(Kg + ch * 512 + l * 8, &KC[0][ch * 512 + l * 8]);
    async16(Vg + ch * 512 + l * 8, &VC[0][ch * 512 + l * 8]);
  }
  const int s = qt * 128 + w * 32 + i32;
  bf16x8 qf[4];
#pragma unroll
  for (int ks = 0; ks < 4; ks++)
    qf[ks] = *(const bf16x8*)(Qg + ((s >> 6) * 8 + ks * 2 + hi) * 512 + (s & 63) * 8);
  __syncthreads();

  float lsum = 0.f;
  f32x16 oacc[2];
#pragma unroll
  for (int r = 0; r < 16; r++) { oacc[0][r] = 0.f; oacc[1][r] = 0.f; }

#pragma unroll 1
  for (int kv = 0; kv < 16; kv++) {
    int cur = kv & 1, nxt = cur ^ 1;
    if (kv < 15) {                   // prefetch next K/V; drained by end-of-iter barrier
#pragma unroll
      for (int p = 0; p < 2; p++) {
        int ch = w + 4 * p;
        async16(Kg + (kv + 1) * 4096 + ch * 512 + l * 8, &KC[nxt][ch * 512 + l * 8]);
        async16(Vg + (kv + 1) * 4096 + ch * 512 + l * 8, &VC[nxt][ch * 512 + l * 8]);
      }
    }

#pragma unroll
    for (int jt = 0; jt < 2; jt++) {
      // S^T [32 j][32 i] for this jt: A = K rows j, B = Q cols i, k-dim d = 4 ks of 16
      f32x16 st;
#pragma unroll
      for (int r = 0; r < 16; r++) st[r] = 0.f;
#pragma unroll
      for (int ks = 0; ks < 4; ks++) {
        bf16x8 kf = *(const bf16x8*)(&KC[cur][(ks * 2 + hi) * 512 + (jt * 32 + i32) * 8]);
        st = MFMA32(kf, qf[ks], st);
      }
      // P = exp2(S): reg r holds P[i=i32][j_local = (r&3) + 8*(r>>2) + 4*hi]
      float pr[16];
#pragma unroll
      for (int r = 0; r < 16; r++) pr[r] = __builtin_amdgcn_exp2f(st[r]);
#pragma unroll
      for (int r = 0; r < 16; r += 4) lsum += (pr[r] + pr[r + 1]) + (pr[r + 2] + pr[r + 3]);
      // PV A-frag in registers. For k-slice js_local=h: u = q2=2h packs, v = q2=2h+1 packs.
      // permlane32_swap(vdst=u, vsrc=v): u[l>=32] <- v[l-32], v[l<32] <- u[l+32].
      // After swap, frag {u0,u1,v0,v1} = for hi=0: {own u (j 16h+0..3), partner u (j 16h+4..7)},
      //                                  for hi=1: {partner v (j 16h+8..11), own v (j 16h+12..15)}.
#pragma unroll
      for (int h = 0; h < 2; h++) {
        unsigned u0 = pk2(pr[8 * h + 0], pr[8 * h + 1]);
        unsigned u1 = pk2(pr[8 * h + 2], pr[8 * h + 3]);
        unsigned v0 = pk2(pr[8 * h + 4], pr[8 * h + 5]);
        unsigned v1 = pk2(pr[8 * h + 6], pr[8 * h + 7]);
        asm volatile("v_permlane32_swap_b32 %0, %1" : "+v"(u0), "+v"(v0));
        asm volatile("v_permlane32_swap_b32 %0, %1" : "+v"(u1), "+v"(v1));
        u32x4 dv; dv[0] = u0; dv[1] = u1; dv[2] = v0; dv[3] = v1;
        bf16x8 pf = __builtin_bit_cast(bf16x8, dv);
        int js = jt * 2 + h;
#pragma unroll
        for (int dt = 0; dt < 2; dt++) {
          bf16x8 vf = *(const bf16x8*)(&VC[cur][(js * 2 + hi) * 512 + (dt * 32 + i32) * 8]);
          oacc[dt] = MFMA32(pf, vf, oacc[dt]);
        }
      }
    }
    __syncthreads();     // drains prefetch; cur-buf reads done
  }

  // deferred l reduction: lane l and l^32 hold complementary j-halves of row i=i32
  lsum += __shfl_xor(lsum, 32);
  const float inv = 1.f / lsum;

  // O -> LDS (KC region, free after loop) [n' = (i&15)*64 + d][8 c], c&7 = w*2 + (i>>4)
  char* PO = (char*)KC;
#pragma unroll
  for (int dt = 0; dt < 2; dt++) {
#pragma unroll
    for (int r = 0; r < 8; r++) {
      int ilo = (r & 3) + 8 * (r >> 2) + 4 * hi;     // 0..15
      float iblo = __shfl(inv, ilo);
      float ibhi = __shfl(inv, ilo + 16);
      bf16x2 ov;
      ov[0] = (__bf16)(oacc[dt][r]     * iblo);
      ov[1] = (__bf16)(oacc[dt][r + 8] * ibhi);
      *(bf16x2*)(PO + (ilo * 64 + dt * 32 + i32) * 16 + w * 4) = ov;
    }
  }
  __syncthreads();
  // block output = contiguous 8192 bf16 at pin[(nh*8+qt)][b*1024 .. +1024][8]
  __bf16* Pg = pin + (nh * 8 + qt) * 65536 + b * 8192;
#pragma unroll
  for (int p = 0; p < 4; p++) {
    int idx = p * 256 + tid;
    *(bf16x8*)(Pg + idx * 8) = *(const bf16x8*)((const char*)PO + idx * 16);
  }
}

// ---------------------------------------------------------------- Proj GEMM + residual (64x128 tiles)
__global__ __launch_bounds__(256) void gemm_proj_k(const __bf16* __restrict__ W,
                                                   const float* __restrict__ bias,
                                                   const __bf16* __restrict__ P,
                                                   const float* __restrict__ x,
                                                   float* __restrict__ out) {
  __shared__ __bf16 AL[2][2048];    // [4 ch][64 r][8]
  __shared__ __bf16 BL[2][4096];    // [4 cg][128 r][8]
  const int tid = threadIdx.x;
  const int w = tid >> 6, l = tid & 63, quad = l >> 4, li = l & 15;
  const int wr = w >> 1, wc = w & 1;
  const int mblk = blockIdx.x >> 6, nblk = blockIdx.x & 63;
  const int m0 = mblk * 64, n0 = nblk * 128;

  f32x4 acc[2][4];
#pragma unroll
  for (int i = 0; i < 2; i++)
#pragma unroll
    for (int j = 0; j < 4; j++) acc[i][j] = f32x4{0.f, 0.f, 0.f, 0.f};

  const __bf16* Ag = W + ((mblk * 16) * 4 + w) * 512 + l * 8;
  const __bf16* Bg = P + w * 65536 + (n0 + l) * 8;   // [cg][n][8]; kt stride = 4*65536

  async16(Ag,       &AL[0][w * 512]);
  async16(Bg,       &BL[0][w * 1024]);
  async16(Bg + 512, &BL[0][w * 1024 + 512]);

#pragma unroll 1
  for (int kt = 0; kt < 16; kt++) {
    int cur = kt & 1, nxt = cur ^ 1;
    __syncthreads();
    if (kt < 15) {
      int koA = (kt + 1) * 2048;
      int koB = (kt + 1) * 262144;
      async16(Ag + koA,       &AL[nxt][w * 512]);
      async16(Bg + koB,       &BL[nxt][w * 1024]);
      async16(Bg + koB + 512, &BL[nxt][w * 1024 + 512]);
    }
    bf16x8 af[2], bfr[4];
#pragma unroll
    for (int i = 0; i < 2; i++)
      af[i] = *(const bf16x8*)(&AL[cur][quad * 512 + (wr * 32 + i * 16 + li) * 8]);
#pragma unroll
    for (int j = 0; j < 4; j++)
      bfr[j] = *(const bf16x8*)(&BL[cur][quad * 1024 + (wc * 64 + j * 16 + li) * 8]);
#pragma unroll
    for (int i = 0; i < 2; i++)
#pragma unroll
      for (int j = 0; j < 4; j++) acc[i][j] = MFMA(af[i], bfr[j], acc[i][j]);
  }

  const int bb = n0 >> 10;
#pragma unroll
  for (int mi = 0; mi < 2; mi++) {
    int o = m0 + wr * 32 + mi * 16 + quad * 4;
    float bs[4];
#pragma unroll
    for (int r = 0; r < 4; r++) bs[r] = bias[o + r];
#pragma unroll
    for (int ni = 0; ni < 4; ni++) {
      int n = n0 + wc * 64 + ni * 16 + li;
      int s = n & 1023;
#pragma unroll
      for (int r = 0; r < 4; r++) {
        int a = (bb * 512 + o + r) * 1024 + s;
        out[a] = acc[mi][ni][r] + bs[r] + x[a];
      }
    }
  }
}

// ---------------------------------------------------------------- launch
extern "C" void kernel_launch(void* const* d_in, const int* in_sizes, int n_in,
                              void* d_out, int out_size, void* d_ws, size_t ws_size,
                              hipStream_t stream) {
  const float* x      = (const float*)d_in[0];
  const float* gamma  = (const float*)d_in[1];
  const float* beta   = (const float*)d_in[2];
  const float* qkv_w  = (const float*)d_in[3];
  const float* qkv_b  = (const float*)d_in[4];
  const float* proj_w = (const float*)d_in[5];
  const float* proj_b = (const float*)d_in[6];

  __bf16* ws   = (__bf16*)d_ws;
  __bf16* H    = ws;                 // chunked groupnorm out; reused as P_in [cg][n][8]
  __bf16* qbuf = ws + 4194304;
  __bf16* kbuf = ws + 8388608;
  __bf16* vt   = ws + 12582912;
  __bf16* wq   = ws + 16777216;
  __bf16* wp   = ws + 17563648;

  prep_k<<<768, 512, 0, stream>>>(x, gamma, beta, H, qkv_w, wq, proj_w, wp);
  gemm_qkv_k<<<768, 256, 0, stream>>>(wq, qkv_b, H, qbuf, kbuf, vt);
  attn_k<<<512, 256, 0, stream>>>(qbuf, kbuf, vt, H);
  gemm_proj_k<<<512, 256, 0, stream>>>(wp, proj_b, H, x, (float*)d_out);
}